// Round 8
// baseline (1311.625 us; speedup 1.0000x reference)
//
#include <hip/hip_runtime.h>
#include <math.h>

#define N_LOCS 16384
#define START 4096
#define NB 12288
#define NMAT 96
#define KDIM 60

typedef __attribute__((ext_vector_type(8))) short short8;
typedef __attribute__((ext_vector_type(4))) float f32x4;

__global__ void minnz_kernel(const float* __restrict__ scales, unsigned* __restrict__ ws) {
    int idx = blockIdx.x * 256 + threadIdx.x;
    if (idx < NB) {
        float v = scales[START + idx];
        if (v != 0.0f) atomicMin(ws, __float_as_uint(v));
    }
}

__device__ __forceinline__ unsigned short f32_to_bf16_rne(float f, float* back) {
    unsigned u = __float_as_uint(f);
    unsigned r = (u + 0x7fffu + ((u >> 16) & 1u)) >> 16;
    *back = __uint_as_float(r << 16);
    return (unsigned short)r;
}

__launch_bounds__(256)
__global__ void fused_kernel(const float* __restrict__ kp,
                             const float* __restrict__ aug,
                             const float* __restrict__ scales,
                             const float* __restrict__ nug,
                             const unsigned* __restrict__ ws,
                             float* __restrict__ out)
{
    const int b = blockIdx.x;
    const int t = threadIdx.x;
    const int ti = t >> 4, tj = t & 15;

    float* outG = out;                                   // [NB][96][96]
    float* outL = out + (size_t)NB * NMAT * NMAT;        // [NB][96][96]
    float* outN = out + 2 * (size_t)NB * NMAT * NMAT;    // [NB]

    if (t == 0) outN[b] = nug[b];

    const size_t gbase = (size_t)b * (NMAT * NMAT);

    if (b == 0) {
        // reference: g[0] = I, chol(I) = I
        #pragma unroll
        for (int u = 0; u < 6; ++u) {
            int i = ti * 6 + u;
            #pragma unroll
            for (int v = 0; v < 6; ++v) {
                int j = tj * 6 + v;
                float e = (i == j) ? 1.0f : 0.0f;
                outG[gbase + (size_t)i * NMAT + j] = e;
                outL[gbase + (size_t)i * NMAT + j] = e;
            }
        }
        return;
    }

    // ---- overlaid LDS union (phases: x-stage -> lin dump -> chol) ----
    __shared__ char smem[37632];
    unsigned short* sxh  = (unsigned short*)smem;
    unsigned short* sxl  = (unsigned short*)(smem + 13824);
    float*          slin = (float*)smem;
    // chol phase (overlays slin after it's dead):
    float*          spanel = (float*)smem;            // [96][12] padded panel (48B rows)
    float*          sL6    = (float*)(smem + 4608);   // [6][8] factored diag tile
    float*          srinv  = (float*)(smem + 4800);   // [6]

    // ---- scalar parameters (r=1, R=2 per setup_inputs) ----
    const float kp1 = kp[1], kp3 = kp[3], kp5 = kp[5], kp7 = kp[7];
    const float kp8 = kp[8], kp9 = kp[9], kp11 = kp[11];
    float sc = scales[START + b];
    if (sc == 0.0f) sc = __uint_as_float(ws[0]) * 0.5f;
    const float sigma   = __expf(kp1 + kp3 * __logf(sc));
    const float sigma2  = sigma * sigma;
    const float inv_ls2 = 1.0f / (3.0f * __expf(2.0f * kp11));  // ls^2 = 3*exp(2*kp11)
    const float inv_nug = 1.0f / nug[b];

    // ---- per-lane scaling coefficient (lane owns column c of x) ----
    const int c = t & 63;
    float myscale = 0.0f;
    if (c < KDIM) {
        float kf = (c < 30) ? (float)(c + 1) : (float)(c - 29);
        float th = (c < 30) ? kp5 : kp8;
        float de = (c < 30) ? kp7 : kp9;
        myscale = __expf(th - 0.5f * __expf(de) * kf);
    }

    // ---- stage x into LDS as split-bf16: x~ = hi + lo; k padded 60->64 with zeros ----
    {
        const int rgrp = t >> 6;  // 0..3 (4 rows per iteration)
        const size_t rowstride = (size_t)N_LOCS * 61;
        const size_t base = (size_t)(START + b) * 61 + 1 + c;
        for (int it = 0; it < 24; ++it) {
            int i = it * 4 + rgrp;
            float v = 0.0f;
            if (c < KDIM) {
                v = aug[base + (size_t)i * rowstride];
                v = (v != v) ? 0.0f : v;
                v *= myscale;
            }
            float fh;
            unsigned short hb = f32_to_bf16_rne(v, &fh);
            float dummy;
            unsigned short lb = f32_to_bf16_rne(v - fh, &dummy);
            sxh[i * 72 + c] = hb;
            sxl[i * 72 + c] = lb;
        }
    }
    __syncthreads();

    // ---- gram via MFMA: 4 waves, each a 48x48 quadrant = 3x3 tiles of 16x16 ----
    // 4-term split: hh + hl + lh + ll == Gram(hi+lo) exactly -> distances genuine -> PSD.
    // BOTH A and B fragments streamed (4 live frags = 16 VGPRs, was 48) so total
    // VGPR+AGPR lands <=128 naturally -> 16 waves/CU. Per-accumulator MFMA chain
    // order unchanged from r5 (hh,hl,lh,ll per k0; k0 ascending) -> bitwise same.
    {
        const int w  = t >> 6;
        const int l  = t & 63;
        const int wrB = (w >> 1) * 48;   // row base
        const int wcB = (w & 1) * 48;    // col base
        const int lrow = l & 15;
        const int lk   = (l >> 4) * 8;

        f32x4 gacc[3][3];
        #pragma unroll
        for (int a = 0; a < 3; ++a)
            #pragma unroll
            for (int cc = 0; cc < 3; ++cc) gacc[a][cc] = (f32x4){0.f, 0.f, 0.f, 0.f};

        #pragma unroll
        for (int k0 = 0; k0 < 64; k0 += 32) {
            #pragma unroll
            for (int a = 0; a < 3; ++a) {
                int arow = wrB + a * 16 + lrow;
                short8 Ah = *(const short8*)&sxh[arow * 72 + k0 + lk];
                short8 Al = *(const short8*)&sxl[arow * 72 + k0 + lk];
                #pragma unroll
                for (int cc = 0; cc < 3; ++cc) {
                    int brow = wcB + cc * 16 + lrow;
                    short8 Bh = *(const short8*)&sxh[brow * 72 + k0 + lk];
                    short8 Bl = *(const short8*)&sxl[brow * 72 + k0 + lk];
                    gacc[a][cc] = __builtin_amdgcn_mfma_f32_16x16x32_bf16(Ah, Bh, gacc[a][cc], 0, 0, 0);
                    gacc[a][cc] = __builtin_amdgcn_mfma_f32_16x16x32_bf16(Ah, Bl, gacc[a][cc], 0, 0, 0);
                    gacc[a][cc] = __builtin_amdgcn_mfma_f32_16x16x32_bf16(Al, Bh, gacc[a][cc], 0, 0, 0);
                    gacc[a][cc] = __builtin_amdgcn_mfma_f32_16x16x32_bf16(Al, Bl, gacc[a][cc], 0, 0, 0);
                }
            }
        }
        __syncthreads();   // all frag reads done before overwriting x region with lin

        // dump: C layout col = lane&15, row = (lane>>4)*4 + reg  [m89/m91]
        #pragma unroll
        for (int a = 0; a < 3; ++a)
            #pragma unroll
            for (int cc = 0; cc < 3; ++cc) {
                int col = wcB + cc * 16 + lrow;
                #pragma unroll
                for (int r = 0; r < 4; ++r) {
                    int row = wrB + a * 16 + (l >> 4) * 4 + r;
                    slin[row * 98 + col] = gacc[a][cc][r];
                }
            }
    }
    __syncthreads();

    // ---- read 6x6 tile + diag from slin ----
    float acc[6][6];
    #pragma unroll
    for (int u = 0; u < 6; ++u) {
        int rb = (ti * 6 + u) * 98;
        #pragma unroll
        for (int v = 0; v < 6; v += 2) {
            float2 p = *(const float2*)&slin[rb + tj * 6 + v];
            acc[u][v] = p.x; acc[u][v + 1] = p.y;
        }
    }
    float di[6], dj[6];
    #pragma unroll
    for (int u = 0; u < 6; ++u) { int i = ti * 6 + u; di[u] = slin[i * 98 + i]; }
    #pragma unroll
    for (int v = 0; v < 6; ++v) { int j = tj * 6 + v; dj[v] = slin[j * 98 + j]; }
    __syncthreads();   // slin dead; chol arrays may overlay it

    // ---- transform to g = (linear + sigma^2*(1+c)exp(-c))/nug + I ----
    #pragma unroll
    for (int u = 0; u < 6; ++u) {
        int i = ti * 6 + u;
        #pragma unroll
        for (int v = 0; v < 6; ++v) {
            int j = tj * 6 + v;
            float lin = acc[u][v];
            float d2 = (di[u] + dj[v] - 2.0f * lin) * inv_ls2;
            d2 = fmaxf(d2, 0.0f);
            float cc = sqrtf(3.0f * d2);
            float nl = (1.0f + cc) * __expf(-cc);
            acc[u][v] = fmaf(sigma2, nl, lin) * inv_nug + ((i == j) ? 1.0f : 0.0f);
        }
    }

    // ---- write g (float2 stores) ----
    #pragma unroll
    for (int u = 0; u < 6; ++u) {
        size_t row = gbase + (size_t)(ti * 6 + u) * NMAT + tj * 6;
        #pragma unroll
        for (int v = 0; v < 6; v += 2) {
            *(float2*)&outG[row + v] = make_float2(acc[u][v], acc[u][v + 1]);
        }
    }

    // ---- blocked cholesky (block=6), round-5 structure (VERIFIED) ----
    for (int jb = 0; jb < 16; ++jb) {
        // Phase A: owner factors its own 6x6 in registers
        if (ti == jb && tj == jb) {
            #pragma unroll
            for (int c2 = 0; c2 < 6; ++c2) {
                float s = acc[c2][c2];
                #pragma unroll
                for (int m = 0; m < 6; ++m) if (m < c2) s -= acc[c2][m] * acc[c2][m];
                float l = sqrtf(s);
                acc[c2][c2] = l;
                float rinv = 1.0f / l;
                srinv[c2] = rinv;
                #pragma unroll
                for (int rr = 0; rr < 6; ++rr) if (rr > c2) {
                    float s2 = acc[rr][c2];
                    #pragma unroll
                    for (int m = 0; m < 6; ++m) if (m < c2) s2 -= acc[rr][m] * acc[c2][m];
                    acc[rr][c2] = s2 * rinv;
                }
            }
            // publish factored tile rows (lower triangle valid; upper stale-unused)
            #pragma unroll
            for (int u = 0; u < 6; ++u) {
                *(float4*)&sL6[u * 8]     = make_float4(acc[u][0], acc[u][1], acc[u][2], acc[u][3]);
                *(float2*)&sL6[u * 8 + 4] = make_float2(acc[u][4], acc[u][5]);
            }
        }
        __syncthreads();
        // Phase B: panel solve, diag tile in registers, vector publish
        if (tj == jb && ti > jb) {
            float A6[6][6], rinv6[6];
            #pragma unroll
            for (int u = 0; u < 6; ++u) {
                float4 p = *(const float4*)&sL6[u * 8];
                float2 q = *(const float2*)&sL6[u * 8 + 4];
                A6[u][0] = p.x; A6[u][1] = p.y; A6[u][2] = p.z; A6[u][3] = p.w;
                A6[u][4] = q.x; A6[u][5] = q.y;
            }
            #pragma unroll
            for (int c2 = 0; c2 < 6; ++c2) rinv6[c2] = srinv[c2];
            #pragma unroll
            for (int u = 0; u < 6; ++u) {
                #pragma unroll
                for (int c2 = 0; c2 < 6; ++c2) {
                    float s = acc[u][c2];
                    #pragma unroll
                    for (int m = 0; m < 6; ++m) if (m < c2) s -= acc[u][m] * A6[c2][m];
                    acc[u][c2] = s * rinv6[c2];
                }
                int row = ti * 6 + u;
                *(float4*)&spanel[row * 12]     = make_float4(acc[u][0], acc[u][1], acc[u][2], acc[u][3]);
                *(float2*)&spanel[row * 12 + 4] = make_float2(acc[u][4], acc[u][5]);
            }
        }
        __syncthreads();
        // Phase C: trailing rank-6 update with vector panel reads
        if (tj > jb && ti >= tj) {
            float pv[6][6];
            #pragma unroll
            for (int v = 0; v < 6; ++v) {
                int row = tj * 6 + v;
                float4 p = *(const float4*)&spanel[row * 12];
                float2 q = *(const float2*)&spanel[row * 12 + 4];
                pv[v][0] = p.x; pv[v][1] = p.y; pv[v][2] = p.z; pv[v][3] = p.w;
                pv[v][4] = q.x; pv[v][5] = q.y;
            }
            #pragma unroll
            for (int u = 0; u < 6; ++u) {
                int row = ti * 6 + u;
                float4 p = *(const float4*)&spanel[row * 12];
                float2 q = *(const float2*)&spanel[row * 12 + 4];
                float pu0 = p.x, pu1 = p.y, pu2 = p.z, pu3 = p.w, pu4 = q.x, pu5 = q.y;
                #pragma unroll
                for (int v = 0; v < 6; ++v) {
                    float s = acc[u][v];
                    s = fmaf(-pu0, pv[v][0], s);
                    s = fmaf(-pu1, pv[v][1], s);
                    s = fmaf(-pu2, pv[v][2], s);
                    s = fmaf(-pu3, pv[v][3], s);
                    s = fmaf(-pu4, pv[v][4], s);
                    s = fmaf(-pu5, pv[v][5], s);
                    acc[u][v] = s;
                }
            }
        }
    }

    // ---- write chol (upper tiles = 0, diag tiles upper-zeroed) ----
    #pragma unroll
    for (int u = 0; u < 6; ++u) {
        int i = ti * 6 + u;
        size_t row = gbase + (size_t)i * NMAT + tj * 6;
        #pragma unroll
        for (int v = 0; v < 6; v += 2) {
            int j0 = tj * 6 + v;
            float a0 = acc[u][v], a1 = acc[u][v + 1];
            if (ti < tj) { a0 = 0.0f; a1 = 0.0f; }
            else if (ti == tj) {
                if (j0 > i)     a0 = 0.0f;
                if (j0 + 1 > i) a1 = 0.0f;
            }
            *(float2*)&outL[row + v] = make_float2(a0, a1);
        }
    }
}

extern "C" void kernel_launch(void* const* d_in, const int* in_sizes, int n_in,
                              void* d_out, int out_size, void* d_ws, size_t ws_size,
                              hipStream_t stream) {
    const float* kp     = (const float*)d_in[0];
    const float* aug    = (const float*)d_in[1];
    const float* scales = (const float*)d_in[2];
    const float* nug    = (const float*)d_in[3];
    float* out = (float*)d_out;
    unsigned* ws = (unsigned*)d_ws;

    // sentinel = 0xFFFFFFFF (max uint) for the nonzero-min reduction
    hipMemsetAsync(ws, 0xFF, 4, stream);
    minnz_kernel<<<(NB + 255) / 256, 256, 0, stream>>>(scales, ws);
    fused_kernel<<<NB, 256, 0, stream>>>(kp, aug, scales, nug, ws, out);
}

// Round 9
// 1094.472 us; speedup vs baseline: 1.1984x; 1.1984x over previous
//
#include <hip/hip_runtime.h>
#include <math.h>

#define N_LOCS 16384
#define START 4096
#define NB 12288
#define NMAT 96
#define KDIM 60

typedef __attribute__((ext_vector_type(8))) short short8;
typedef __attribute__((ext_vector_type(4))) float f32x4;

__global__ void minnz_kernel(const float* __restrict__ scales, unsigned* __restrict__ ws) {
    int idx = blockIdx.x * 256 + threadIdx.x;
    if (idx < NB) {
        float v = scales[START + idx];
        if (v != 0.0f) atomicMin(ws, __float_as_uint(v));
    }
}

__device__ __forceinline__ unsigned short f32_to_bf16_rne(float f, float* back) {
    unsigned u = __float_as_uint(f);
    unsigned r = (u + 0x7fffu + ((u >> 16) & 1u)) >> 16;
    *back = __uint_as_float(r << 16);
    return (unsigned short)r;
}

// ============ kernel 1: gram + transform + write g (r8-verified code) ============
__launch_bounds__(256)
__global__ void gram_kernel(const float* __restrict__ kp,
                            const float* __restrict__ aug,
                            const float* __restrict__ scales,
                            const float* __restrict__ nug,
                            const unsigned* __restrict__ ws,
                            float* __restrict__ out)
{
    const int b = blockIdx.x;
    const int t = threadIdx.x;
    const int ti = t >> 4, tj = t & 15;

    float* outG = out;                                   // [NB][96][96]
    float* outN = out + 2 * (size_t)NB * NMAT * NMAT;    // [NB]

    if (t == 0) outN[b] = nug[b];

    const size_t gbase = (size_t)b * (NMAT * NMAT);

    if (b == 0) {
        // reference: g[0] = I (chol kernel will factor I -> I)
        #pragma unroll
        for (int u = 0; u < 6; ++u) {
            int i = ti * 6 + u;
            #pragma unroll
            for (int v = 0; v < 6; ++v) {
                int j = tj * 6 + v;
                outG[gbase + (size_t)i * NMAT + j] = (i == j) ? 1.0f : 0.0f;
            }
        }
        return;
    }

    // ---- overlaid LDS union (x-stage -> lin dump) ----
    __shared__ char smem[37632];
    unsigned short* sxh  = (unsigned short*)smem;
    unsigned short* sxl  = (unsigned short*)(smem + 13824);
    float*          slin = (float*)smem;

    // ---- scalar parameters (r=1, R=2 per setup_inputs) ----
    const float kp1 = kp[1], kp3 = kp[3], kp5 = kp[5], kp7 = kp[7];
    const float kp8 = kp[8], kp9 = kp[9], kp11 = kp[11];
    float sc = scales[START + b];
    if (sc == 0.0f) sc = __uint_as_float(ws[0]) * 0.5f;
    const float sigma   = __expf(kp1 + kp3 * __logf(sc));
    const float sigma2  = sigma * sigma;
    const float inv_ls2 = 1.0f / (3.0f * __expf(2.0f * kp11));  // ls^2 = 3*exp(2*kp11)
    const float inv_nug = 1.0f / nug[b];

    // ---- per-lane scaling coefficient (lane owns column c of x) ----
    const int c = t & 63;
    float myscale = 0.0f;
    if (c < KDIM) {
        float kf = (c < 30) ? (float)(c + 1) : (float)(c - 29);
        float th = (c < 30) ? kp5 : kp8;
        float de = (c < 30) ? kp7 : kp9;
        myscale = __expf(th - 0.5f * __expf(de) * kf);
    }

    // ---- stage x into LDS as split-bf16: x~ = hi + lo; k padded 60->64 with zeros ----
    {
        const int rgrp = t >> 6;  // 0..3 (4 rows per iteration)
        const size_t rowstride = (size_t)N_LOCS * 61;
        const size_t base = (size_t)(START + b) * 61 + 1 + c;
        for (int it = 0; it < 24; ++it) {
            int i = it * 4 + rgrp;
            float v = 0.0f;
            if (c < KDIM) {
                v = aug[base + (size_t)i * rowstride];
                v = (v != v) ? 0.0f : v;
                v *= myscale;
            }
            float fh;
            unsigned short hb = f32_to_bf16_rne(v, &fh);
            float dummy;
            unsigned short lb = f32_to_bf16_rne(v - fh, &dummy);
            sxh[i * 72 + c] = hb;
            sxl[i * 72 + c] = lb;
        }
    }
    __syncthreads();

    // ---- gram via MFMA: 4 waves, each a 48x48 quadrant = 3x3 tiles of 16x16 ----
    // 4-term split: hh + hl + lh + ll == Gram(hi+lo) exactly -> distances genuine -> PSD.
    {
        const int w  = t >> 6;
        const int l  = t & 63;
        const int wrB = (w >> 1) * 48;   // row base
        const int wcB = (w & 1) * 48;    // col base
        const int lrow = l & 15;
        const int lk   = (l >> 4) * 8;

        f32x4 gacc[3][3];
        #pragma unroll
        for (int a = 0; a < 3; ++a)
            #pragma unroll
            for (int cc = 0; cc < 3; ++cc) gacc[a][cc] = (f32x4){0.f, 0.f, 0.f, 0.f};

        #pragma unroll
        for (int k0 = 0; k0 < 64; k0 += 32) {
            #pragma unroll
            for (int a = 0; a < 3; ++a) {
                int arow = wrB + a * 16 + lrow;
                short8 Ah = *(const short8*)&sxh[arow * 72 + k0 + lk];
                short8 Al = *(const short8*)&sxl[arow * 72 + k0 + lk];
                #pragma unroll
                for (int cc = 0; cc < 3; ++cc) {
                    int brow = wcB + cc * 16 + lrow;
                    short8 Bh = *(const short8*)&sxh[brow * 72 + k0 + lk];
                    short8 Bl = *(const short8*)&sxl[brow * 72 + k0 + lk];
                    gacc[a][cc] = __builtin_amdgcn_mfma_f32_16x16x32_bf16(Ah, Bh, gacc[a][cc], 0, 0, 0);
                    gacc[a][cc] = __builtin_amdgcn_mfma_f32_16x16x32_bf16(Ah, Bl, gacc[a][cc], 0, 0, 0);
                    gacc[a][cc] = __builtin_amdgcn_mfma_f32_16x16x32_bf16(Al, Bh, gacc[a][cc], 0, 0, 0);
                    gacc[a][cc] = __builtin_amdgcn_mfma_f32_16x16x32_bf16(Al, Bl, gacc[a][cc], 0, 0, 0);
                }
            }
        }
        __syncthreads();   // all frag reads done before overwriting x region with lin

        // dump: C layout col = lane&15, row = (lane>>4)*4 + reg  [m89/m91]
        #pragma unroll
        for (int a = 0; a < 3; ++a)
            #pragma unroll
            for (int cc = 0; cc < 3; ++cc) {
                int col = wcB + cc * 16 + lrow;
                #pragma unroll
                for (int r = 0; r < 4; ++r) {
                    int row = wrB + a * 16 + (l >> 4) * 4 + r;
                    slin[row * 98 + col] = gacc[a][cc][r];
                }
            }
    }
    __syncthreads();

    // ---- read 6x6 tile + diag from slin ----
    float acc[6][6];
    #pragma unroll
    for (int u = 0; u < 6; ++u) {
        int rb = (ti * 6 + u) * 98;
        #pragma unroll
        for (int v = 0; v < 6; v += 2) {
            float2 p = *(const float2*)&slin[rb + tj * 6 + v];
            acc[u][v] = p.x; acc[u][v + 1] = p.y;
        }
    }
    float di[6], dj[6];
    #pragma unroll
    for (int u = 0; u < 6; ++u) { int i = ti * 6 + u; di[u] = slin[i * 98 + i]; }
    #pragma unroll
    for (int v = 0; v < 6; ++v) { int j = tj * 6 + v; dj[v] = slin[j * 98 + j]; }

    // ---- transform to g = (linear + sigma^2*(1+c)exp(-c))/nug + I, write g ----
    #pragma unroll
    for (int u = 0; u < 6; ++u) {
        int i = ti * 6 + u;
        #pragma unroll
        for (int v = 0; v < 6; ++v) {
            int j = tj * 6 + v;
            float lin = acc[u][v];
            float d2 = (di[u] + dj[v] - 2.0f * lin) * inv_ls2;
            d2 = fmaxf(d2, 0.0f);
            float cc = sqrtf(3.0f * d2);
            float nl = (1.0f + cc) * __expf(-cc);
            acc[u][v] = fmaf(sigma2, nl, lin) * inv_nug + ((i == j) ? 1.0f : 0.0f);
        }
    }
    #pragma unroll
    for (int u = 0; u < 6; ++u) {
        size_t row = gbase + (size_t)(ti * 6 + u) * NMAT + tj * 6;
        #pragma unroll
        for (int v = 0; v < 6; v += 2) {
            *(float2*)&outG[row + v] = make_float2(acc[u][v], acc[u][v + 1]);
        }
    }
}

// ============ kernel 2: cholesky (r5/r8-verified structure), reads g from outG ============
__launch_bounds__(256)
__global__ void chol_kernel(const float* __restrict__ outG,
                            float* __restrict__ outL)
{
    const int b = blockIdx.x;
    const int t = threadIdx.x;
    const int ti = t >> 4, tj = t & 15;
    const size_t gbase = (size_t)b * (NMAT * NMAT);

    __shared__ float spanel[NMAT * 12];   // [96][12] padded panel (48B rows)
    __shared__ float sL6[6 * 8];          // factored diag tile
    __shared__ float srinv[6];

    // ---- load my 6x6 tile of g ----
    float acc[6][6];
    #pragma unroll
    for (int u = 0; u < 6; ++u) {
        size_t row = gbase + (size_t)(ti * 6 + u) * NMAT + tj * 6;
        #pragma unroll
        for (int v = 0; v < 6; v += 2) {
            float2 p = *(const float2*)&outG[row + v];
            acc[u][v] = p.x; acc[u][v + 1] = p.y;
        }
    }

    // ---- blocked cholesky (block=6), round-5 structure (VERIFIED) ----
    for (int jb = 0; jb < 16; ++jb) {
        // Phase A: owner factors its own 6x6 in registers
        if (ti == jb && tj == jb) {
            #pragma unroll
            for (int c2 = 0; c2 < 6; ++c2) {
                float s = acc[c2][c2];
                #pragma unroll
                for (int m = 0; m < 6; ++m) if (m < c2) s -= acc[c2][m] * acc[c2][m];
                float l = sqrtf(s);
                acc[c2][c2] = l;
                float rinv = 1.0f / l;
                srinv[c2] = rinv;
                #pragma unroll
                for (int rr = 0; rr < 6; ++rr) if (rr > c2) {
                    float s2 = acc[rr][c2];
                    #pragma unroll
                    for (int m = 0; m < 6; ++m) if (m < c2) s2 -= acc[rr][m] * acc[c2][m];
                    acc[rr][c2] = s2 * rinv;
                }
            }
            #pragma unroll
            for (int u = 0; u < 6; ++u) {
                *(float4*)&sL6[u * 8]     = make_float4(acc[u][0], acc[u][1], acc[u][2], acc[u][3]);
                *(float2*)&sL6[u * 8 + 4] = make_float2(acc[u][4], acc[u][5]);
            }
        }
        __syncthreads();
        // Phase B: panel solve, diag tile in registers, vector publish
        if (tj == jb && ti > jb) {
            float A6[6][6], rinv6[6];
            #pragma unroll
            for (int u = 0; u < 6; ++u) {
                float4 p = *(const float4*)&sL6[u * 8];
                float2 q = *(const float2*)&sL6[u * 8 + 4];
                A6[u][0] = p.x; A6[u][1] = p.y; A6[u][2] = p.z; A6[u][3] = p.w;
                A6[u][4] = q.x; A6[u][5] = q.y;
            }
            #pragma unroll
            for (int c2 = 0; c2 < 6; ++c2) rinv6[c2] = srinv[c2];
            #pragma unroll
            for (int u = 0; u < 6; ++u) {
                #pragma unroll
                for (int c2 = 0; c2 < 6; ++c2) {
                    float s = acc[u][c2];
                    #pragma unroll
                    for (int m = 0; m < 6; ++m) if (m < c2) s -= acc[u][m] * A6[c2][m];
                    acc[u][c2] = s * rinv6[c2];
                }
                int row = ti * 6 + u;
                *(float4*)&spanel[row * 12]     = make_float4(acc[u][0], acc[u][1], acc[u][2], acc[u][3]);
                *(float2*)&spanel[row * 12 + 4] = make_float2(acc[u][4], acc[u][5]);
            }
        }
        __syncthreads();
        // Phase C: trailing rank-6 update with vector panel reads
        if (tj > jb && ti >= tj) {
            float pv[6][6];
            #pragma unroll
            for (int v = 0; v < 6; ++v) {
                int row = tj * 6 + v;
                float4 p = *(const float4*)&spanel[row * 12];
                float2 q = *(const float2*)&spanel[row * 12 + 4];
                pv[v][0] = p.x; pv[v][1] = p.y; pv[v][2] = p.z; pv[v][3] = p.w;
                pv[v][4] = q.x; pv[v][5] = q.y;
            }
            #pragma unroll
            for (int u = 0; u < 6; ++u) {
                int row = ti * 6 + u;
                float4 p = *(const float4*)&spanel[row * 12];
                float2 q = *(const float2*)&spanel[row * 12 + 4];
                float pu0 = p.x, pu1 = p.y, pu2 = p.z, pu3 = p.w, pu4 = q.x, pu5 = q.y;
                #pragma unroll
                for (int v = 0; v < 6; ++v) {
                    float s = acc[u][v];
                    s = fmaf(-pu0, pv[v][0], s);
                    s = fmaf(-pu1, pv[v][1], s);
                    s = fmaf(-pu2, pv[v][2], s);
                    s = fmaf(-pu3, pv[v][3], s);
                    s = fmaf(-pu4, pv[v][4], s);
                    s = fmaf(-pu5, pv[v][5], s);
                    acc[u][v] = s;
                }
            }
        }
    }

    // ---- write chol (upper tiles = 0, diag tiles upper-zeroed) ----
    #pragma unroll
    for (int u = 0; u < 6; ++u) {
        int i = ti * 6 + u;
        size_t row = gbase + (size_t)i * NMAT + tj * 6;
        #pragma unroll
        for (int v = 0; v < 6; v += 2) {
            int j0 = tj * 6 + v;
            float a0 = acc[u][v], a1 = acc[u][v + 1];
            if (ti < tj) { a0 = 0.0f; a1 = 0.0f; }
            else if (ti == tj) {
                if (j0 > i)     a0 = 0.0f;
                if (j0 + 1 > i) a1 = 0.0f;
            }
            *(float2*)&outL[row + v] = make_float2(a0, a1);
        }
    }
}

extern "C" void kernel_launch(void* const* d_in, const int* in_sizes, int n_in,
                              void* d_out, int out_size, void* d_ws, size_t ws_size,
                              hipStream_t stream) {
    const float* kp     = (const float*)d_in[0];
    const float* aug    = (const float*)d_in[1];
    const float* scales = (const float*)d_in[2];
    const float* nug    = (const float*)d_in[3];
    float* out = (float*)d_out;
    unsigned* ws = (unsigned*)d_ws;

    float* outG = out;
    float* outL = out + (size_t)NB * NMAT * NMAT;

    // sentinel = 0xFFFFFFFF (max uint) for the nonzero-min reduction
    hipMemsetAsync(ws, 0xFF, 4, stream);
    minnz_kernel<<<(NB + 255) / 256, 256, 0, stream>>>(scales, ws);
    gram_kernel<<<NB, 256, 0, stream>>>(kp, aug, scales, nug, ws, out);
    chol_kernel<<<NB, 256, 0, stream>>>(outG, outL);
}